// Round 10
// baseline (403.465 us; speedup 1.0000x reference)
//
#include <hip/hip_runtime.h>
#include <hip/hip_bf16.h>

// SimilarityLayer: out[e,q,w,n,m] = <p[e,w,:,n], q[e,q,:,m]> / (|p||q| + 1e-8)
// E=8 W=5 C=640 N=49 Q=75.
// R10: B K-chunk (query[eq, 32c:32c+32, :]) is CONTIGUOUS (1568 floats, 16B
//      aligned) -> stage as 392 coalesced float4 into fp32 LDS (5x fewer VMEM
//      insts than R9's strided scalars). Fragments built by stride-49 LDS reads
//      (2-way bank alias = free) + in-reg cvt (x4 redundant, hides latency).
//      A from fragment-ordered aimg. Double-buffer LDS, T14 issue-early/
//      write-late, 1 barrier/chunk, fully unrolled. q-norms via shfl_xor.

#define E_CNT 8
#define W_CNT 5
#define C_CNT 640
#define N_CNT 49
#define Q_CNT 75
#define MROWS 245                    // W*N
#define NC32 20                      // K chunks of 32
#define CHF 1568                     // floats per B chunk (32 x 49)
#define AFRAG_CH 16384               // per (e,chunk): 16 row-tiles x 64 lanes x 16B
#define AIMG_E (NC32 * AFRAG_CH)     // 327,680 B per e
#define AIMG_SIZE (E_CNT * AIMG_E)   // 2,621,440
#define PN_OFF AIMG_SIZE
#define PN_BYTES (E_CNT * 10 * MROWS * 4)
#define WS1 ((size_t)(PN_OFF + PN_BYTES))

typedef __attribute__((ext_vector_type(8))) short bf16x8;
typedef __attribute__((ext_vector_type(4))) float f32x4;

static __device__ __forceinline__ short f2bf(float f) {
    __hip_bfloat16 h = __float2bfloat16(f);
    return *reinterpret_cast<short*>(&h);
}

// ---------------- prep_a: proto -> fragment-ordered bf16 A image + partials --
__global__ __launch_bounds__(256, 4)
void prep_a_kernel(const float* __restrict__ proto,
                   unsigned char* __restrict__ aimg,
                   float* __restrict__ pn_part)
{
    __shared__ float pns[MROWS];
    const int b = blockIdx.x;            // 80 = e*10 + c64
    const int e = b / 10, c64 = b % 10;
    const float* pbase = proto + (size_t)e * (W_CNT * C_CNT * N_CNT);
    unsigned char* ebase = aimg + (size_t)e * AIMG_E;
    const int t = threadIdx.x;
    if (t < MROWS) pns[t] = 0.f;
    __syncthreads();

    #pragma unroll
    for (int i = 0; i < 8; ++i) {
        const int s = t + i * 256;       // slot = kb*245 + nw, kb in [0,8)
        int nw, kb;
        bf16x8 pk;
        if (s < 8 * MROWS) {
            kb = s / MROWS;
            nw = s - kb * MROWS;
            const int w = nw / N_CNT, n = nw - w * N_CNT;
            const float* g = pbase + ((size_t)(w * C_CNT + c64 * 64 + kb * 8)) * N_CNT + n;
            float ss = 0.f;
            #pragma unroll
            for (int j = 0; j < 8; ++j) {
                const float f = g[(size_t)j * N_CNT];
                ss += f * f;
                pk[j] = f2bf(f);
            }
            atomicAdd(&pns[nw], ss);
        } else {
            const int x = s - 8 * MROWS; // zero-pad rows 245..255
            nw = MROWS + (x >> 3);
            kb = x & 7;
            pk = (bf16x8){0, 0, 0, 0, 0, 0, 0, 0};
        }
        const int c32 = c64 * 2 + (kb >> 2);
        const int ln2 = ((kb & 3) << 4) | (nw & 15);
        *reinterpret_cast<bf16x8*>(
            ebase + (size_t)c32 * AFRAG_CH + (size_t)((nw >> 4) * 64 + ln2) * 16) = pk;
    }
    __syncthreads();
    if (t < MROWS) pn_part[(size_t)(e * 10 + c64) * MROWS + t] = pns[t];
}

// ---------------- gemm4: coalesced fp32-LDS B staging + direct-consume cvt ---
__global__ __launch_bounds__(256, 4)
void gemm4_kernel(const float* __restrict__ query,
                  const unsigned char* __restrict__ aimg,
                  const float* __restrict__ pn_part,
                  float* __restrict__ out)
{
    __shared__ __align__(16) float Bst[2][CHF];   // fp32 chunk, double-buffered
    __shared__ float pnl[128];

    const int b = blockIdx.x;            // 1200
    const int e = b & 7;                 // same e -> same XCD; mh pair same XCD too
    const int mh = (b >> 3) & 1;         // M-half: rows [mh*128, +128)
    const int q = b >> 4;                // 0..74
    const int eq = e * Q_CNT + q;
    const int t = threadIdx.x;
    const int wv = t >> 6, ln = t & 63;
    const int lrow = ln & 15, lk = ln >> 4;

    const float* __restrict__ qsl = query + (size_t)eq * (C_CNT * N_CNT);

    // A fragments: this wave's 2 row-tiles
    const int rt0 = mh * 8 + wv * 2;
    const unsigned char* __restrict__ abase =
        aimg + (size_t)e * AIMG_E + (size_t)(rt0 * 64 + ln) * 16;

    // per-fj LDS column (clamped; clamped lanes masked at write)
    int colv[4];
    #pragma unroll
    for (int fj = 0; fj < 4; ++fj) {
        const int c_ = fj * 16 + lrow;
        colv[fj] = (c_ < N_CNT) ? c_ : (N_CNT - 1);
    }

    // p-norms for this block's 128 rows (barrier inside loop covers the hazard)
    if (t < 128) {
        const int row = mh * 128 + t;
        float s = 0.f;
        if (row < MROWS) {
            #pragma unroll
            for (int cc = 0; cc < 10; ++cc)
                s += pn_part[(size_t)(e * 10 + cc) * MROWS + row];
        }
        pnl[t] = sqrtf(s);
    }

    const bool t2 = t < (CHF / 4 - 256);         // 136 threads carry a 2nd float4
    f32x4 vq0, vq1;
    bf16x8 afA[2], afB[2];
    f32x4 acc[2][4];
    #pragma unroll
    for (int i = 0; i < 2; ++i)
        #pragma unroll
        for (int j = 0; j < 4; ++j) acc[i][j] = (f32x4){0.f, 0.f, 0.f, 0.f};
    float ssq[4] = {0.f, 0.f, 0.f, 0.f};

#define G4_BLOAD(c) do {                                                        \
    const float* cs_ = qsl + (size_t)(c) * CHF;                                 \
    vq0 = *reinterpret_cast<const f32x4*>(cs_ + t * 4);                         \
    if (t2) vq1 = *reinterpret_cast<const f32x4*>(cs_ + 1024 + t * 4);          \
} while (0)

#define G4_BWRITE(c) do {                                                       \
    float* bd_ = Bst[(c) & 1];                                                  \
    *reinterpret_cast<f32x4*>(bd_ + t * 4) = vq0;                               \
    if (t2) *reinterpret_cast<f32x4*>(bd_ + 1024 + t * 4) = vq1;                \
} while (0)

#define G4_ALOAD(c, dst) do {                                                   \
    _Pragma("unroll")                                                           \
    for (int fi_ = 0; fi_ < 2; ++fi_)                                           \
        dst[fi_] = *reinterpret_cast<const bf16x8*>(                            \
            abase + (size_t)(c) * AFRAG_CH + fi_ * 1024);                       \
} while (0)

    // prologue: chunk 0 staged
    G4_BLOAD(0);
    G4_ALOAD(0, afA);
    G4_BWRITE(0);
    __syncthreads();

    #pragma unroll
    for (int c = 0; c < NC32; ++c) {     // fully unrolled: parities static
        // issue next chunk's loads (land during compute below)
        if (c + 1 < NC32) {
            G4_BLOAD(c + 1);
            if (c & 1) G4_ALOAD(c + 1, afA); else G4_ALOAD(c + 1, afB);
        }

        // build B fragments from LDS fp32 (stride-49 reads: 2-way alias, free)
        const float* __restrict__ bb = Bst[c & 1];
        bf16x8 bfr[4];
        #pragma unroll
        for (int fj = 0; fj < 4; ++fj) {
            float s8 = 0.f;
            #pragma unroll
            for (int j = 0; j < 8; ++j) {
                const float f = bb[colv[fj] + (lk * 8 + j) * N_CNT];
                s8 += f * f;
                bfr[fj][j] = f2bf(f);
            }
            ssq[fj] += s8;
        }

        // MFMA
        {
            const bf16x8* af = (c & 1) ? afB : afA;
            #pragma unroll
            for (int fi = 0; fi < 2; ++fi)
                #pragma unroll
                for (int fj = 0; fj < 4; ++fj)
                    acc[fi][fj] = __builtin_amdgcn_mfma_f32_16x16x32_bf16(
                        af[fi], bfr[fj], acc[fi][fj], 0, 0, 0);
        }

        // write next chunk (loads had the whole compute phase to land)
        if (c + 1 < NC32) {
            G4_BWRITE(c + 1);
            __syncthreads();
        }
    }

    // ---- q-norms: reduce ssq over the 4 lk groups (every wave gets full sum) --
    float nq4[4];
    #pragma unroll
    for (int fj = 0; fj < 4; ++fj) {
        float s = ssq[fj];
        s += __shfl_xor(s, 16);
        s += __shfl_xor(s, 32);
        nq4[fj] = sqrtf(s);
    }

    // ---- epilogue: rows mh*128 + wv*32 + fi*16 + lk*4 + rr ; cols fj*16+lrow --
    float* __restrict__ osl = out + (size_t)eq * (W_CNT * N_CNT * N_CNT);
    #pragma unroll
    for (int fi = 0; fi < 2; ++fi) {
        #pragma unroll
        for (int rr = 0; rr < 4; ++rr) {
            const int lr = wv * 32 + fi * 16 + lk * 4 + rr;
            const int row = mh * 128 + lr;
            if (row < MROWS) {
                const float np_ = pnl[lr];
                #pragma unroll
                for (int fj = 0; fj < 4; ++fj) {
                    const int m = fj * 16 + lrow;
                    if (m < N_CNT) {
                        const float den = np_ * nq4[fj] + 1e-8f;
                        osl[row * N_CNT + m] = acc[fi][fj][rr] * __builtin_amdgcn_rcpf(den);
                    }
                }
            }
        }
    }
#undef G4_BLOAD
#undef G4_BWRITE
#undef G4_ALOAD
}

// ---------------- tier-0 fallback (R2 kernel, no ws) -------------------------
struct SMemFB {
    unsigned char A[256 * 128];
    unsigned char B[64 * 128];
    float ns[320];
};

__global__ __launch_bounds__(512, 4)
void sim_fallback_kernel(const float* __restrict__ proto,
                         const float* __restrict__ query,
                         float* __restrict__ out)
{
    __shared__ SMemFB smf;
    const int t = threadIdx.x;
    const int e = blockIdx.x / Q_CNT;
    const int q = blockIdx.x - e * Q_CNT;
    const float* pbase = proto + (size_t)e * (W_CNT * C_CNT * N_CNT);
    const float* qbase = query + ((size_t)e * Q_CNT + q) * (C_CNT * N_CNT);
    unsigned char* lds = (unsigned char*)&smf;
    if (t < 320) smf.ns[t] = 0.f;
    if (t < 208) {
        if (t < 88) *reinterpret_cast<f32x4*>(smf.A + 245 * 128 + t * 16) = (f32x4){0.f,0.f,0.f,0.f};
        else        *reinterpret_cast<f32x4*>(smf.B + 49 * 128 + (t - 88) * 16) = (f32x4){0.f,0.f,0.f,0.f};
    }
    const int nslot5 = (t < 304);
    const float* gp[5];
    int offidx[5];
    #pragma unroll
    for (int i = 0; i < 5; ++i) {
        gp[i] = pbase; offidx[i] = 0;
        if (i < 4 || nslot5) {
            const int s = t + i * 512;
            if (s < 1960) {
                const int kb = s / 245, nw = s - kb * 245;
                const int w = nw / 49, n = nw - w * 49;
                gp[i] = pbase + ((size_t)w * C_CNT + kb * 8) * N_CNT + n;
                offidx[i] = (nw * 128 + ((kb ^ (nw & 7)) << 4)) | (nw << 16);
            } else {
                const int s2 = s - 1960;
                const int kb = s2 / 49, mq = s2 - kb * 49;
                gp[i] = qbase + (size_t)(kb * 8) * N_CNT + mq;
                offidx[i] = (32768 + mq * 128 + ((kb ^ (mq & 7)) << 4)) | ((256 + mq) << 16);
            }
        }
    }
    float v[5][8];
    float ss[5] = {0.f,0.f,0.f,0.f,0.f};
    #pragma unroll
    for (int i = 0; i < 4; ++i)
        #pragma unroll
        for (int j = 0; j < 8; ++j) v[i][j] = gp[i][(size_t)j * N_CNT];
    if (nslot5)
        #pragma unroll
        for (int j = 0; j < 8; ++j) v[4][j] = gp[4][(size_t)j * N_CNT];
    f32x4 acc[2][4];
    #pragma unroll
    for (int i = 0; i < 2; ++i)
        #pragma unroll
        for (int j = 0; j < 4; ++j) acc[i][j] = (f32x4){0.f,0.f,0.f,0.f};
    const int wv = t >> 6, ln = t & 63, lrow = ln & 15, lk = ln >> 4;
    for (int kc = 0; kc < 10; ++kc) {
        #pragma unroll
        for (int i = 0; i < 5; ++i) {
            if (i < 4 || nslot5) {
                bf16x8 pk; float s8 = 0.f;
                #pragma unroll
                for (int j = 0; j < 8; ++j) { const float f = v[i][j]; s8 += f*f; pk[j] = f2bf(f); }
                ss[i] += s8;
                *reinterpret_cast<bf16x8*>(lds + (offidx[i] & 0xFFFF)) = pk;
            }
        }
        __syncthreads();
        if (kc < 9) {
            #pragma unroll
            for (int i = 0; i < 4; ++i) {
                gp[i] += 64 * N_CNT;
                #pragma unroll
                for (int j = 0; j < 8; ++j) v[i][j] = gp[i][(size_t)j * N_CNT];
            }
            if (nslot5) {
                gp[4] += 64 * N_CNT;
                #pragma unroll
                for (int j = 0; j < 8; ++j) v[4][j] = gp[4][(size_t)j * N_CNT];
            }
        }
        #pragma unroll
        for (int ks = 0; ks < 2; ++ks) {
            bf16x8 af[2], bfr[4];
            #pragma unroll
            for (int i = 0; i < 2; ++i) {
                const int row = (wv * 2 + i) * 16 + lrow;
                const int gr = (ks * 4 + lk) ^ (row & 7);
                af[i] = *reinterpret_cast<const bf16x8*>(lds + row * 128 + gr * 16);
            }
            #pragma unroll
            for (int j = 0; j < 4; ++j) {
                const int mq = j * 16 + lrow;
                const int gr = (ks * 4 + lk) ^ (mq & 7);
                bfr[j] = *reinterpret_cast<const bf16x8*>(lds + 32768 + mq * 128 + gr * 16);
            }
            #pragma unroll
            for (int i = 0; i < 2; ++i)
                #pragma unroll
                for (int j = 0; j < 4; ++j)
                    acc[i][j] = __builtin_amdgcn_mfma_f32_16x16x32_bf16(af[i], bfr[j], acc[i][j], 0, 0, 0);
        }
        __syncthreads();
    }
    #pragma unroll
    for (int i = 0; i < 5; ++i)
        if (i < 4 || nslot5) atomicAdd(&smf.ns[offidx[i] >> 16], ss[i]);
    __syncthreads();
    float nq[4];
    #pragma unroll
    for (int j = 0; j < 4; ++j) {
        const int mq = j * 16 + lrow;
        nq[j] = (mq < N_CNT) ? sqrtf(smf.ns[256 + mq]) : 1.f;
    }
    float* obase = out + (size_t)(e * Q_CNT + q) * (W_CNT * N_CNT * N_CNT);
    #pragma unroll
    for (int i = 0; i < 2; ++i) {
        #pragma unroll
        for (int rr = 0; rr < 4; ++rr) {
            const int nw = (wv * 2 + i) * 16 + lk * 4 + rr;
            if (nw < W_CNT * N_CNT) {
                const int w = nw / 49, n = nw - w * 49;
                const float np_ = sqrtf(smf.ns[nw]);
                float* orow = obase + ((size_t)w * N_CNT + n) * N_CNT;
                #pragma unroll
                for (int j = 0; j < 4; ++j) {
                    const int mq = j * 16 + lrow;
                    if (mq < N_CNT) orow[mq] = acc[i][j][rr] / (np_ * nq[j] + 1e-8f);
                }
            }
        }
    }
}

extern "C" void kernel_launch(void* const* d_in, const int* in_sizes, int n_in,
                              void* d_out, int out_size, void* d_ws, size_t ws_size,
                              hipStream_t stream)
{
    const float* proto = (const float*)d_in[0];
    const float* query = (const float*)d_in[1];
    float* out = (float*)d_out;

    if (ws_size < WS1) {
        hipLaunchKernelGGL(sim_fallback_kernel, dim3(E_CNT * Q_CNT), dim3(512), 0, stream,
                           proto, query, out);
        return;
    }

    unsigned char* aimg = (unsigned char*)d_ws;
    float* pn_part = (float*)((unsigned char*)d_ws + PN_OFF);

    hipLaunchKernelGGL(prep_a_kernel, dim3(E_CNT * 10), dim3(256), 0, stream,
                       proto, aimg, pn_part);
    hipLaunchKernelGGL(gemm4_kernel, dim3(E_CNT * Q_CNT * 2), dim3(256), 0, stream,
                       query, aimg, pn_part, out);
}

// Round 11
// 108.559 us; speedup vs baseline: 3.7165x; 3.7165x over previous
//
#include <hip/hip_runtime.h>
#include <hip/hip_bf16.h>

// SimilarityLayer: out[e,q,w,n,m] = <p[e,w,:,n], q[e,q,:,m]> / (|p||q| + 1e-8)
// E=8 W=5 C=640 N=49 Q=75.
// R11: fixes R10's scratch-spill (747MB writes: pointer-ternary demoted A-frag
//      arrays to scratch; now static afr[(c)&1] indexing). Wave = 64 rows x
//      16 cols (ONE B fragment per wave: 8 b32 LDS reads vs 32). Grid 2400
//      (e,q,row-quarter) -> 9.4 waves/SIMD. B chunk staged coalesced float4 ->
//      fp32 LDS, double-buffered; A from fragment-ordered aimg (L2-hot).

#define E_CNT 8
#define W_CNT 5
#define C_CNT 640
#define N_CNT 49
#define Q_CNT 75
#define MROWS 245                    // W*N
#define NC32 20                      // K chunks of 32
#define CHF 1568                     // floats per B chunk (32 x 49)
#define AFRAG_CH 16384               // per (e,chunk): 16 row-tiles x 64 lanes x 16B
#define AIMG_E (NC32 * AFRAG_CH)     // 327,680 B per e
#define AIMG_SIZE (E_CNT * AIMG_E)   // 2,621,440
#define PN_OFF AIMG_SIZE
#define PN_BYTES (E_CNT * 10 * MROWS * 4)
#define WS1 ((size_t)(PN_OFF + PN_BYTES))

typedef __attribute__((ext_vector_type(8))) short bf16x8;
typedef __attribute__((ext_vector_type(4))) float f32x4;

static __device__ __forceinline__ short f2bf(float f) {
    __hip_bfloat16 h = __float2bfloat16(f);
    return *reinterpret_cast<short*>(&h);
}

// ---------------- prep_a: proto -> fragment-ordered bf16 A image + partials --
__global__ __launch_bounds__(256, 4)
void prep_a_kernel(const float* __restrict__ proto,
                   unsigned char* __restrict__ aimg,
                   float* __restrict__ pn_part)
{
    __shared__ float pns[MROWS];
    const int b = blockIdx.x;            // 80 = e*10 + c64
    const int e = b / 10, c64 = b % 10;
    const float* pbase = proto + (size_t)e * (W_CNT * C_CNT * N_CNT);
    unsigned char* ebase = aimg + (size_t)e * AIMG_E;
    const int t = threadIdx.x;
    if (t < MROWS) pns[t] = 0.f;
    __syncthreads();

    #pragma unroll
    for (int i = 0; i < 8; ++i) {
        const int s = t + i * 256;       // slot = kb*245 + nw, kb in [0,8)
        int nw, kb;
        bf16x8 pk;
        if (s < 8 * MROWS) {
            kb = s / MROWS;
            nw = s - kb * MROWS;
            const int w = nw / N_CNT, n = nw - w * N_CNT;
            const float* g = pbase + ((size_t)(w * C_CNT + c64 * 64 + kb * 8)) * N_CNT + n;
            float ss = 0.f;
            #pragma unroll
            for (int j = 0; j < 8; ++j) {
                const float f = g[(size_t)j * N_CNT];
                ss += f * f;
                pk[j] = f2bf(f);
            }
            atomicAdd(&pns[nw], ss);
        } else {
            const int x = s - 8 * MROWS; // zero-pad rows 245..255
            nw = MROWS + (x >> 3);
            kb = x & 7;
            pk = (bf16x8){0, 0, 0, 0, 0, 0, 0, 0};
        }
        const int c32 = c64 * 2 + (kb >> 2);
        const int ln2 = ((kb & 3) << 4) | (nw & 15);
        *reinterpret_cast<bf16x8*>(
            ebase + (size_t)c32 * AFRAG_CH + (size_t)((nw >> 4) * 64 + ln2) * 16) = pk;
    }
    __syncthreads();
    if (t < MROWS) pn_part[(size_t)(e * 10 + c64) * MROWS + t] = pns[t];
}

// ---------------- gemm5: wave = 64 rows x 16 cols, one B frag per wave -------
__global__ __launch_bounds__(256, 4)
void gemm5_kernel(const float* __restrict__ query,
                  const unsigned char* __restrict__ aimg,
                  const float* __restrict__ pn_part,
                  float* __restrict__ out)
{
    __shared__ __align__(16) float Bst[2][CHF];   // fp32 chunk, double-buffered
    __shared__ float pnl[64];

    const int b = blockIdx.x;            // 2400 = e + 8*(mq + 4*q)
    const int e = b & 7;                 // same e -> same XCD (aimg + query L2-hot)
    const int r2 = b >> 3;
    const int mq = r2 & 3;               // 64-row quarter: rows [mq*64, +64)
    const int q = r2 >> 2;               // 0..74
    const int eq = e * Q_CNT + q;
    const int t = threadIdx.x;
    const int wv = t >> 6, ln = t & 63;
    const int lrow = ln & 15, lk = ln >> 4;

    const float* __restrict__ qsl = query + (size_t)eq * (C_CNT * N_CNT);

    // A fragments: this block's 4 row-tiles (shared by all waves, L2-hot)
    const unsigned char* __restrict__ abase =
        aimg + (size_t)e * AIMG_E + (size_t)(mq * 4 * 64 + ln) * 16;

    // this wave's single column group: col = wv*16 + lrow
    const int col = wv * 16 + lrow;
    const int colc = (col < N_CNT) ? col : (N_CNT - 1);   // clamp (masked at write)

    // p-norms for this block's 64 rows (covered by prologue barrier)
    if (t < 64) {
        const int row = mq * 64 + t;
        float s = 0.f;
        if (row < MROWS) {
            #pragma unroll
            for (int cc = 0; cc < 10; ++cc)
                s += pn_part[(size_t)(e * 10 + cc) * MROWS + row];
        }
        pnl[t] = sqrtf(s);
    }

    const bool t2 = t < (CHF / 4 - 256);          // 136 threads carry 2nd float4
    f32x4 vq0, vq1;
    bf16x8 afr[2][4];                             // static-indexed only!
    f32x4 acc[4];
    #pragma unroll
    for (int i = 0; i < 4; ++i) acc[i] = (f32x4){0.f, 0.f, 0.f, 0.f};
    float ssq = 0.f;

#define G5_BLOAD(c) do {                                                        \
    const float* cs_ = qsl + (size_t)(c) * CHF;                                 \
    vq0 = *reinterpret_cast<const f32x4*>(cs_ + t * 4);                         \
    if (t2) vq1 = *reinterpret_cast<const f32x4*>(cs_ + 1024 + t * 4);          \
} while (0)

#define G5_BWRITE(c) do {                                                       \
    float* bd_ = Bst[(c) & 1];                                                  \
    *reinterpret_cast<f32x4*>(bd_ + t * 4) = vq0;                               \
    if (t2) *reinterpret_cast<f32x4*>(bd_ + 1024 + t * 4) = vq1;                \
} while (0)

#define G5_ALOAD(c, p_) do {                                                    \
    _Pragma("unroll")                                                           \
    for (int fi_ = 0; fi_ < 4; ++fi_)                                           \
        afr[p_][fi_] = *reinterpret_cast<const bf16x8*>(                        \
            abase + (size_t)(c) * AFRAG_CH + fi_ * 1024);                       \
} while (0)

    // prologue: chunk 0 staged
    G5_BLOAD(0);
    G5_ALOAD(0, 0);
    G5_BWRITE(0);
    __syncthreads();

    #pragma unroll
    for (int c = 0; c < NC32; ++c) {      // fully unrolled: all parities static
        if (c + 1 < NC32) {
            G5_BLOAD(c + 1);
            G5_ALOAD(c + 1, (c + 1) & 1);
        }

        // build this wave's single B fragment from fp32 LDS
        // banks: (col + 8*lk + 49*j) % 32 -> exact 2-way alias = free
        {
            const float* __restrict__ bb = Bst[c & 1];
            bf16x8 bfr;
            float s8 = 0.f;
            #pragma unroll
            for (int j = 0; j < 8; ++j) {
                const float f = bb[colc + (lk * 8 + j) * N_CNT];
                s8 += f * f;
                bfr[j] = f2bf(f);
            }
            ssq += s8;
            #pragma unroll
            for (int fi = 0; fi < 4; ++fi)
                acc[fi] = __builtin_amdgcn_mfma_f32_16x16x32_bf16(
                    afr[c & 1][fi], bfr, acc[fi], 0, 0, 0);
        }

        if (c + 1 < NC32) {
            G5_BWRITE(c + 1);             // loads had the whole compute to land
            __syncthreads();
        }
    }

    // ---- q-norm for this wave's column: reduce over the 4 lk groups ----
    float nq;
    {
        float s = ssq;
        s += __shfl_xor(s, 16);
        s += __shfl_xor(s, 32);
        nq = sqrtf(s);
    }

    // ---- epilogue: row = mq*64 + fi*16 + lk*4 + rr ; col = wv*16 + lrow ----
    float* __restrict__ osl = out + (size_t)eq * (W_CNT * N_CNT * N_CNT);
    if (col < N_CNT) {
        #pragma unroll
        for (int fi = 0; fi < 4; ++fi) {
            #pragma unroll
            for (int rr = 0; rr < 4; ++rr) {
                const int lr = fi * 16 + lk * 4 + rr;
                const int row = mq * 64 + lr;
                if (row < MROWS) {
                    const float den = pnl[lr] * nq + 1e-8f;
                    osl[row * N_CNT + col] = acc[fi][rr] * __builtin_amdgcn_rcpf(den);
                }
            }
        }
    }
#undef G5_BLOAD
#undef G5_BWRITE
#undef G5_ALOAD
}

// ---------------- tier-0 fallback (R2 kernel, no ws) -------------------------
struct SMemFB {
    unsigned char A[256 * 128];
    unsigned char B[64 * 128];
    float ns[320];
};

__global__ __launch_bounds__(512, 4)
void sim_fallback_kernel(const float* __restrict__ proto,
                         const float* __restrict__ query,
                         float* __restrict__ out)
{
    __shared__ SMemFB smf;
    const int t = threadIdx.x;
    const int e = blockIdx.x / Q_CNT;
    const int q = blockIdx.x - e * Q_CNT;
    const float* pbase = proto + (size_t)e * (W_CNT * C_CNT * N_CNT);
    const float* qbase = query + ((size_t)e * Q_CNT + q) * (C_CNT * N_CNT);
    unsigned char* lds = (unsigned char*)&smf;
    if (t < 320) smf.ns[t] = 0.f;
    if (t < 208) {
        if (t < 88) *reinterpret_cast<f32x4*>(smf.A + 245 * 128 + t * 16) = (f32x4){0.f,0.f,0.f,0.f};
        else        *reinterpret_cast<f32x4*>(smf.B + 49 * 128 + (t - 88) * 16) = (f32x4){0.f,0.f,0.f,0.f};
    }
    const int nslot5 = (t < 304);
    const float* gp[5];
    int offidx[5];
    #pragma unroll
    for (int i = 0; i < 5; ++i) {
        gp[i] = pbase; offidx[i] = 0;
        if (i < 4 || nslot5) {
            const int s = t + i * 512;
            if (s < 1960) {
                const int kb = s / 245, nw = s - kb * 245;
                const int w = nw / 49, n = nw - w * 49;
                gp[i] = pbase + ((size_t)w * C_CNT + kb * 8) * N_CNT + n;
                offidx[i] = (nw * 128 + ((kb ^ (nw & 7)) << 4)) | (nw << 16);
            } else {
                const int s2 = s - 1960;
                const int kb = s2 / 49, mq = s2 - kb * 49;
                gp[i] = qbase + (size_t)(kb * 8) * N_CNT + mq;
                offidx[i] = (32768 + mq * 128 + ((kb ^ (mq & 7)) << 4)) | ((256 + mq) << 16);
            }
        }
    }
    float v[5][8];
    float ss[5] = {0.f,0.f,0.f,0.f,0.f};
    #pragma unroll
    for (int i = 0; i < 4; ++i)
        #pragma unroll
        for (int j = 0; j < 8; ++j) v[i][j] = gp[i][(size_t)j * N_CNT];
    if (nslot5)
        #pragma unroll
        for (int j = 0; j < 8; ++j) v[4][j] = gp[4][(size_t)j * N_CNT];
    f32x4 acc[2][4];
    #pragma unroll
    for (int i = 0; i < 2; ++i)
        #pragma unroll
        for (int j = 0; j < 4; ++j) acc[i][j] = (f32x4){0.f,0.f,0.f,0.f};
    const int wv = t >> 6, ln = t & 63, lrow = ln & 15, lk = ln >> 4;
    for (int kc = 0; kc < 10; ++kc) {
        #pragma unroll
        for (int i = 0; i < 5; ++i) {
            if (i < 4 || nslot5) {
                bf16x8 pk; float s8 = 0.f;
                #pragma unroll
                for (int j = 0; j < 8; ++j) { const float f = v[i][j]; s8 += f*f; pk[j] = f2bf(f); }
                ss[i] += s8;
                *reinterpret_cast<bf16x8*>(lds + (offidx[i] & 0xFFFF)) = pk;
            }
        }
        __syncthreads();
        if (kc < 9) {
            #pragma unroll
            for (int i = 0; i < 4; ++i) {
                gp[i] += 64 * N_CNT;
                #pragma unroll
                for (int j = 0; j < 8; ++j) v[i][j] = gp[i][(size_t)j * N_CNT];
            }
            if (nslot5) {
                gp[4] += 64 * N_CNT;
                #pragma unroll
                for (int j = 0; j < 8; ++j) v[4][j] = gp[4][(size_t)j * N_CNT];
            }
        }
        #pragma unroll
        for (int ks = 0; ks < 2; ++ks) {
            bf16x8 af[2], bfr[4];
            #pragma unroll
            for (int i = 0; i < 2; ++i) {
                const int row = (wv * 2 + i) * 16 + lrow;
                const int gr = (ks * 4 + lk) ^ (row & 7);
                af[i] = *reinterpret_cast<const bf16x8*>(lds + row * 128 + gr * 16);
            }
            #pragma unroll
            for (int j = 0; j < 4; ++j) {
                const int mq = j * 16 + lrow;
                const int gr = (ks * 4 + lk) ^ (mq & 7);
                bfr[j] = *reinterpret_cast<const bf16x8*>(lds + 32768 + mq * 128 + gr * 16);
            }
            #pragma unroll
            for (int i = 0; i < 2; ++i)
                #pragma unroll
                for (int j = 0; j < 4; ++j)
                    acc[i][j] = __builtin_amdgcn_mfma_f32_16x16x32_bf16(af[i], bfr[j], acc[i][j], 0, 0, 0);
        }
        __syncthreads();
    }
    #pragma unroll
    for (int i = 0; i < 5; ++i)
        if (i < 4 || nslot5) atomicAdd(&smf.ns[offidx[i] >> 16], ss[i]);
    __syncthreads();
    float nq[4];
    #pragma unroll
    for (int j = 0; j < 4; ++j) {
        const int mq = j * 16 + lrow;
        nq[j] = (mq < N_CNT) ? sqrtf(smf.ns[256 + mq]) : 1.f;
    }
    float* obase = out + (size_t)(e * Q_CNT + q) * (W_CNT * N_CNT * N_CNT);
    #pragma unroll
    for (int i = 0; i < 2; ++i) {
        #pragma unroll
        for (int rr = 0; rr < 4; ++rr) {
            const int nw = (wv * 2 + i) * 16 + lk * 4 + rr;
            if (nw < W_CNT * N_CNT) {
                const int w = nw / 49, n = nw - w * 49;
                const float np_ = sqrtf(smf.ns[nw]);
                float* orow = obase + ((size_t)w * N_CNT + n) * N_CNT;
                #pragma unroll
                for (int j = 0; j < 4; ++j) {
                    const int mq = j * 16 + lrow;
                    if (mq < N_CNT) orow[mq] = acc[i][j][rr] / (np_ * nq[j] + 1e-8f);
                }
            }
        }
    }
}

extern "C" void kernel_launch(void* const* d_in, const int* in_sizes, int n_in,
                              void* d_out, int out_size, void* d_ws, size_t ws_size,
                              hipStream_t stream)
{
    const float* proto = (const float*)d_in[0];
    const float* query = (const float*)d_in[1];
    float* out = (float*)d_out;

    if (ws_size < WS1) {
        hipLaunchKernelGGL(sim_fallback_kernel, dim3(E_CNT * Q_CNT), dim3(512), 0, stream,
                           proto, query, out);
        return;
    }

    unsigned char* aimg = (unsigned char*)d_ws;
    float* pn_part = (float*)((unsigned char*)d_ws + PN_OFF);

    hipLaunchKernelGGL(prep_a_kernel, dim3(E_CNT * 10), dim3(256), 0, stream,
                       proto, aimg, pn_part);
    hipLaunchKernelGGL(gemm5_kernel, dim3(2400), dim3(256), 0, stream,
                       query, aimg, pn_part, out);
}

// Round 12
// 39.065 us; speedup vs baseline: 10.3280x; 2.7789x over previous
//
#include <hip/hip_runtime.h>
#include <hip/hip_bf16.h>

// SimilarityLayer: out[e,q,w,n,m] = <p[e,w,:,n], q[e,q,:,m]> / (|p||q| + 1e-8)
// E=8 W=5 C=640 N=49 Q=75.
// R12: R9's proven structure (best: 38.8us) + T4 counted-barrier fix:
//      __syncthreads() emitted vmcnt(0), draining the just-issued c+2 prefetch
//      (~600cyc x 20 chunks). Now: raw "s_waitcnt lgkmcnt(0); s_barrier" --
//      VMEM prefetches stay in flight across barriers; compiler's own
//      register-dep vmcnt covers vB uses. LDS B double-buffered (write is
//      one barrier after last reader), A-frags 2-buffer issued 1 ahead.
//      R10/R11 lesson: NO pointer ternaries / runtime-indexed reg arrays.

#define E_CNT 8
#define W_CNT 5
#define C_CNT 640
#define N_CNT 49
#define Q_CNT 75
#define MROWS 245                    // W*N
#define NC32 20                      // K chunks of 32
#define AFRAG_CH 16384               // per (e,chunk): 16 row-tiles x 64 lanes x 16B
#define AIMG_E (NC32 * AFRAG_CH)     // 327,680 B per e
#define AIMG_SIZE (E_CNT * AIMG_E)   // 2,621,440
#define PN_OFF AIMG_SIZE
#define PN_BYTES (E_CNT * 10 * MROWS * 4)
#define WS1 ((size_t)(PN_OFF + PN_BYTES))

typedef __attribute__((ext_vector_type(8))) short bf16x8;
typedef __attribute__((ext_vector_type(4))) float f32x4;

static __device__ __forceinline__ short f2bf(float f) {
    __hip_bfloat16 h = __float2bfloat16(f);
    return *reinterpret_cast<short*>(&h);
}

// ---------------- prep_a: proto -> fragment-ordered bf16 A image + partials --
__global__ __launch_bounds__(256, 4)
void prep_a_kernel(const float* __restrict__ proto,
                   unsigned char* __restrict__ aimg,
                   float* __restrict__ pn_part)
{
    __shared__ float pns[MROWS];
    const int b = blockIdx.x;            // 80 = e*10 + c64
    const int e = b / 10, c64 = b % 10;
    const float* pbase = proto + (size_t)e * (W_CNT * C_CNT * N_CNT);
    unsigned char* ebase = aimg + (size_t)e * AIMG_E;
    const int t = threadIdx.x;
    if (t < MROWS) pns[t] = 0.f;
    __syncthreads();

    #pragma unroll
    for (int i = 0; i < 8; ++i) {
        const int s = t + i * 256;       // slot = kb*245 + nw, kb in [0,8)
        int nw, kb;
        bf16x8 pk;
        if (s < 8 * MROWS) {
            kb = s / MROWS;
            nw = s - kb * MROWS;
            const int w = nw / N_CNT, n = nw - w * N_CNT;
            const float* g = pbase + ((size_t)(w * C_CNT + c64 * 64 + kb * 8)) * N_CNT + n;
            float ss = 0.f;
            #pragma unroll
            for (int j = 0; j < 8; ++j) {
                const float f = g[(size_t)j * N_CNT];
                ss += f * f;
                pk[j] = f2bf(f);
            }
            atomicAdd(&pns[nw], ss);
        } else {
            const int x = s - 8 * MROWS; // zero-pad rows 245..255
            nw = MROWS + (x >> 3);
            kb = x & 7;
            pk = (bf16x8){0, 0, 0, 0, 0, 0, 0, 0};
        }
        const int c32 = c64 * 2 + (kb >> 2);
        const int ln2 = ((kb & 3) << 4) | (nw & 15);
        *reinterpret_cast<bf16x8*>(
            ebase + (size_t)c32 * AFRAG_CH + (size_t)((nw >> 4) * 64 + ln2) * 16) = pk;
    }
    __syncthreads();
    if (t < MROWS) pn_part[(size_t)(e * 10 + c64) * MROWS + t] = pns[t];
}

// ---------------- gemm6: R9 structure + no-drain barriers --------------------
__global__ __launch_bounds__(256, 4)
void gemm6_kernel(const float* __restrict__ query,
                  const unsigned char* __restrict__ aimg,
                  const float* __restrict__ pn_part,
                  float* __restrict__ out)
{
    __shared__ __align__(16) unsigned char Bbuf[2 * 4096];  // 2 x (4 fj x 64 lanes x 16B)
    __shared__ float qn[64];
    __shared__ float pnl[128];

    const int b = blockIdx.x;            // 1200
    const int e = b & 7;                 // same e -> same XCD -> aimg L2-hot
    const int mh = (b >> 3) & 1;         // M-half: rows [mh*128, +128)
    const int q = b >> 4;                // 0..74
    const int eq = e * Q_CNT + q;
    const int t = threadIdx.x;
    const int wv = t >> 6, ln = t & 63;
    const int lrow = ln & 15, lk = ln >> 4;

    const float* __restrict__ qsl = query + (size_t)eq * (C_CNT * N_CNT);

    // B staging: thread t owns fragment granule (fj = wv, lane = ln):
    //   col = wv*16 + lrow, k-group = lk (8 consecutive k)
    const int scol = wv * 16 + lrow;
    const int scolc = (scol < N_CNT) ? scol : (N_CNT - 1);  // clamp; cols>=49 unused
    const float* __restrict__ sbase = qsl + (size_t)(lk * 8) * N_CNT + scolc;
    const int swoff = wv * 1024 + ln * 16;   // linear dest within one 4K buffer

    // A fragments: this wave's 2 row-tiles
    const int rt0 = mh * 8 + wv * 2;
    const unsigned char* __restrict__ abase =
        aimg + (size_t)e * AIMG_E + (size_t)(rt0 * 64 + ln) * 16;

    // p-norms for this block's 128 rows (loop barriers cover the hazard)
    if (t < 128) {
        const int row = mh * 128 + t;
        float s = 0.f;
        if (row < MROWS) {
            #pragma unroll
            for (int cc = 0; cc < 10; ++cc)
                s += pn_part[(size_t)(e * 10 + cc) * MROWS + row];
        }
        pnl[t] = sqrtf(s);
    }

    float vB[2][8];                      // raw fp32 B, 2-deep (chunk parity)
    bf16x8 afr[2][2];                    // A frags, 2-deep, static indices only
    f32x4 acc[2][4];
    #pragma unroll
    for (int i = 0; i < 2; ++i)
        #pragma unroll
        for (int j = 0; j < 4; ++j) acc[i][j] = (f32x4){0.f, 0.f, 0.f, 0.f};
    float ssq = 0.f;

// Barrier WITHOUT vmcnt drain (T4): ds_write visibility only.
#define G6_BARRIER() asm volatile("s_waitcnt lgkmcnt(0)\n\ts_barrier" ::: "memory")

#define G6_BISSUE(c, s_) do {                                                   \
    _Pragma("unroll")                                                           \
    for (int j_ = 0; j_ < 8; ++j_)                                              \
        vB[s_][j_] = sbase[(size_t)((c) * 32 + j_) * N_CNT];                    \
} while (0)

#define G6_AISSUE(c, s_) do {                                                   \
    _Pragma("unroll")                                                           \
    for (int fi_ = 0; fi_ < 2; ++fi_)                                           \
        afr[s_][fi_] = *reinterpret_cast<const bf16x8*>(                        \
            abase + (size_t)(c) * AFRAG_CH + fi_ * 1024);                       \
} while (0)

#define G6_CVTW(s_, buf) do {                                                   \
    bf16x8 pk_;                                                                 \
    _Pragma("unroll")                                                           \
    for (int j_ = 0; j_ < 8; ++j_) {                                            \
        const float f_ = vB[s_][j_]; ssq += f_ * f_; pk_[j_] = f2bf(f_);        \
    }                                                                           \
    *reinterpret_cast<bf16x8*>(Bbuf + (buf) * 4096 + swoff) = pk_;              \
} while (0)

    // prologue: chunks 0,1 B-loads in flight; A0 in flight; chunk 0 staged
    G6_BISSUE(0, 0);
    G6_AISSUE(0, 0);
    G6_BISSUE(1, 1);
    G6_CVTW(0, 0);
    G6_BARRIER();

    #pragma unroll
    for (int c = 0; c < NC32; ++c) {     // fully unrolled: all parities static
        if (c + 2 < NC32) G6_BISSUE(c + 2, c & 1);   // vB[c&1] dead (cvt'd at c-1)
        if (c + 1 < NC32) G6_AISSUE(c + 1, (c + 1) & 1);

        // MFMA on chunk c: B frags from Bbuf[c&1], A frags afr[c&1]
        {
            const unsigned char* bb = Bbuf + (c & 1) * 4096;
            bf16x8 bfr[4];
            #pragma unroll
            for (int fj = 0; fj < 4; ++fj)
                bfr[fj] = *reinterpret_cast<const bf16x8*>(bb + fj * 1024 + ln * 16);
            #pragma unroll
            for (int fi = 0; fi < 2; ++fi)
                #pragma unroll
                for (int fj = 0; fj < 4; ++fj)
                    acc[fi][fj] = __builtin_amdgcn_mfma_f32_16x16x32_bf16(
                        afr[c & 1][fi], bfr[fj], acc[fi][fj], 0, 0, 0);
        }

        // stage chunk c+1 (its loads were issued at iter c-1: fully landed or
        // compiler-waited via register deps) + no-drain barrier
        if (c + 1 < NC32) {
            G6_CVTW((c + 1) & 1, (c + 1) & 1);
            G6_BARRIER();
        }
    }

    // ---- q-norms: reduce ssq over the 4 lk groups of each column ----
    {
        float s = ssq;
        s += __shfl_xor(s, 16);
        s += __shfl_xor(s, 32);
        if (lk == 0) qn[wv * 16 + lrow] = s;     // col = wv*16 + lrow
    }
    __syncthreads();

    // ---- epilogue: rows mh*128 + wv*32 + fi*16 + lk*4 + rr ; cols fj*16+lrow ----
    float nq4[4];
    #pragma unroll
    for (int fj = 0; fj < 4; ++fj) {
        const int m = fj * 16 + lrow;
        nq4[fj] = (m < N_CNT) ? sqrtf(qn[m]) : 1.f;
    }
    float* __restrict__ osl = out + (size_t)eq * (W_CNT * N_CNT * N_CNT);
    #pragma unroll
    for (int fi = 0; fi < 2; ++fi) {
        #pragma unroll
        for (int rr = 0; rr < 4; ++rr) {
            const int lr = wv * 32 + fi * 16 + lk * 4 + rr;  // row within half
            const int row = mh * 128 + lr;
            if (row < MROWS) {
                const float np_ = pnl[lr];
                #pragma unroll
                for (int fj = 0; fj < 4; ++fj) {
                    const int m = fj * 16 + lrow;
                    if (m < N_CNT) {
                        const float den = np_ * nq4[fj] + 1e-8f;
                        osl[row * N_CNT + m] = acc[fi][fj][rr] * __builtin_amdgcn_rcpf(den);
                    }
                }
            }
        }
    }
#undef G6_BARRIER
#undef G6_BISSUE
#undef G6_AISSUE
#undef G6_CVTW
}

// ---------------- tier-0 fallback (R2 kernel, no ws) -------------------------
struct SMemFB {
    unsigned char A[256 * 128];
    unsigned char B[64 * 128];
    float ns[320];
};

__global__ __launch_bounds__(512, 4)
void sim_fallback_kernel(const float* __restrict__ proto,
                         const float* __restrict__ query,
                         float* __restrict__ out)
{
    __shared__ SMemFB smf;
    const int t = threadIdx.x;
    const int e = blockIdx.x / Q_CNT;
    const int q = blockIdx.x - e * Q_CNT;
    const float* pbase = proto + (size_t)e * (W_CNT * C_CNT * N_CNT);
    const float* qbase = query + ((size_t)e * Q_CNT + q) * (C_CNT * N_CNT);
    unsigned char* lds = (unsigned char*)&smf;
    if (t < 320) smf.ns[t] = 0.f;
    if (t < 208) {
        if (t < 88) *reinterpret_cast<f32x4*>(smf.A + 245 * 128 + t * 16) = (f32x4){0.f,0.f,0.f,0.f};
        else        *reinterpret_cast<f32x4*>(smf.B + 49 * 128 + (t - 88) * 16) = (f32x4){0.f,0.f,0.f,0.f};
    }
    const int nslot5 = (t < 304);
    const float* gp[5];
    int offidx[5];
    #pragma unroll
    for (int i = 0; i < 5; ++i) {
        gp[i] = pbase; offidx[i] = 0;
        if (i < 4 || nslot5) {
            const int s = t + i * 512;
            if (s < 1960) {
                const int kb = s / 245, nw = s - kb * 245;
                const int w = nw / 49, n = nw - w * 49;
                gp[i] = pbase + ((size_t)w * C_CNT + kb * 8) * N_CNT + n;
                offidx[i] = (nw * 128 + ((kb ^ (nw & 7)) << 4)) | (nw << 16);
            } else {
                const int s2 = s - 1960;
                const int kb = s2 / 49, mq = s2 - kb * 49;
                gp[i] = qbase + (size_t)(kb * 8) * N_CNT + mq;
                offidx[i] = (32768 + mq * 128 + ((kb ^ (mq & 7)) << 4)) | ((256 + mq) << 16);
            }
        }
    }
    float v[5][8];
    float ss[5] = {0.f,0.f,0.f,0.f,0.f};
    #pragma unroll
    for (int i = 0; i < 4; ++i)
        #pragma unroll
        for (int j = 0; j < 8; ++j) v[i][j] = gp[i][(size_t)j * N_CNT];
    if (nslot5)
        #pragma unroll
        for (int j = 0; j < 8; ++j) v[4][j] = gp[4][(size_t)j * N_CNT];
    f32x4 acc[2][4];
    #pragma unroll
    for (int i = 0; i < 2; ++i)
        #pragma unroll
        for (int j = 0; j < 4; ++j) acc[i][j] = (f32x4){0.f,0.f,0.f,0.f};
    const int wv = t >> 6, ln = t & 63, lrow = ln & 15, lk = ln >> 4;
    for (int kc = 0; kc < 10; ++kc) {
        #pragma unroll
        for (int i = 0; i < 5; ++i) {
            if (i < 4 || nslot5) {
                bf16x8 pk; float s8 = 0.f;
                #pragma unroll
                for (int j = 0; j < 8; ++j) { const float f = v[i][j]; s8 += f*f; pk[j] = f2bf(f); }
                ss[i] += s8;
                *reinterpret_cast<bf16x8*>(lds + (offidx[i] & 0xFFFF)) = pk;
            }
        }
        __syncthreads();
        if (kc < 9) {
            #pragma unroll
            for (int i = 0; i < 4; ++i) {
                gp[i] += 64 * N_CNT;
                #pragma unroll
                for (int j = 0; j < 8; ++j) v[i][j] = gp[i][(size_t)j * N_CNT];
            }
            if (nslot5) {
                gp[4] += 64 * N_CNT;
                #pragma unroll
                for (int j = 0; j < 8; ++j) v[4][j] = gp[4][(size_t)j * N_CNT];
            }
        }
        #pragma unroll
        for (int ks = 0; ks < 2; ++ks) {
            bf16x8 af[2], bfr[4];
            #pragma unroll
            for (int i = 0; i < 2; ++i) {
                const int row = (wv * 2 + i) * 16 + lrow;
                const int gr = (ks * 4 + lk) ^ (row & 7);
                af[i] = *reinterpret_cast<const bf16x8*>(lds + row * 128 + gr * 16);
            }
            #pragma unroll
            for (int j = 0; j < 4; ++j) {
                const int mq = j * 16 + lrow;
                const int gr = (ks * 4 + lk) ^ (mq & 7);
                bfr[j] = *reinterpret_cast<const bf16x8*>(lds + 32768 + mq * 128 + gr * 16);
            }
            #pragma unroll
            for (int i = 0; i < 2; ++i)
                #pragma unroll
                for (int j = 0; j < 4; ++j)
                    acc[i][j] = __builtin_amdgcn_mfma_f32_16x16x32_bf16(af[i], bfr[j], acc[i][j], 0, 0, 0);
        }
        __syncthreads();
    }
    #pragma unroll
    for (int i = 0; i < 5; ++i)
        if (i < 4 || nslot5) atomicAdd(&smf.ns[offidx[i] >> 16], ss[i]);
    __syncthreads();
    float nq[4];
    #pragma unroll
    for (int j = 0; j < 4; ++j) {
        const int mq = j * 16 + lrow;
        nq[j] = (mq < N_CNT) ? sqrtf(smf.ns[256 + mq]) : 1.f;
    }
    float* obase = out + (size_t)(e * Q_CNT + q) * (W_CNT * N_CNT * N_CNT);
    #pragma unroll
    for (int i = 0; i < 2; ++i) {
        #pragma unroll
        for (int rr = 0; rr < 4; ++rr) {
            const int nw = (wv * 2 + i) * 16 + lk * 4 + rr;
            if (nw < W_CNT * N_CNT) {
                const int w = nw / 49, n = nw - w * 49;
                const float np_ = sqrtf(smf.ns[nw]);
                float* orow = obase + ((size_t)w * N_CNT + n) * N_CNT;
                #pragma unroll
                for (int j = 0; j < 4; ++j) {
                    const int mq = j * 16 + lrow;
                    if (mq < N_CNT) orow[mq] = acc[i][j][rr] / (np_ * nq[j] + 1e-8f);
                }
            }
        }
    }
}

extern "C" void kernel_launch(void* const* d_in, const int* in_sizes, int n_in,
                              void* d_out, int out_size, void* d_ws, size_t ws_size,
                              hipStream_t stream)
{
    const float* proto = (const float*)d_in[0];
    const float* query = (const float*)d_in[1];
    float* out = (float*)d_out;

    if (ws_size < WS1) {
        hipLaunchKernelGGL(sim_fallback_kernel, dim3(E_CNT * Q_CNT), dim3(512), 0, stream,
                           proto, query, out);
        return;
    }

    unsigned char* aimg = (unsigned char*)d_ws;
    float* pn_part = (float*)((unsigned char*)d_ws + PN_OFF);

    hipLaunchKernelGGL(prep_a_kernel, dim3(E_CNT * 10), dim3(256), 0, stream,
                       proto, aimg, pn_part);
    hipLaunchKernelGGL(gemm6_kernel, dim3(E_CNT * Q_CNT * 2), dim3(256), 0, stream,
                       query, aimg, pn_part, out);
}